// Round 1
// baseline (591.157 us; speedup 1.0000x reference)
//
#include <hip/hip_runtime.h>
#include <hip/hip_bf16.h>

typedef unsigned short u16;
typedef __attribute__((ext_vector_type(8))) unsigned short u16x8;
typedef __attribute__((ext_vector_type(8))) short short8;
typedef __attribute__((ext_vector_type(4))) float f32x4;

// ---------- constants ----------
#define MROWS 2048      // B*L
#define VCOLS 32000
#define HDIM  64
#define HID   256
#define KTOT  448       // 64 freq + 64 cos + 64 sin + 256 x
#define ASTRIDE 448
#define BSTRIDE 448

__device__ __forceinline__ u16 f2bf(float f) {
    union { float f; unsigned u; } x; x.f = f;
    unsigned r = x.u + 0x7FFF + ((x.u >> 16) & 1);
    return (u16)(r >> 16);
}

__device__ __forceinline__ float gelu_exact(float v) {
    return 0.5f * v * (1.0f + erff(v * 0.70710678118654752f));
}

// ---------- kernel 1: per-row prep (stats + MLP + A matrix) ----------
#define RP_ROWS 8
__global__ __launch_bounds__(256) void row_prep(
    const float* __restrict__ wr,
    const float* __restrict__ W0, const float* __restrict__ b0,
    const float* __restrict__ W1, const float* __restrict__ b1,
    const float* __restrict__ W2, const float* __restrict__ b2,
    const float* __restrict__ rw,
    u16* __restrict__ Ag, float* __restrict__ rowstats)
{
    __shared__ float in_s[RP_ROWS * 192];
    __shared__ float x_s[RP_ROWS * 256];
    __shared__ float y_s[RP_ROWS * 256];
    __shared__ float la_s[RP_ROWS];

    const int t = threadIdx.x;
    const int r0 = blockIdx.x * RP_ROWS;

    for (int i = t; i < RP_ROWS * 192; i += 256)
        in_s[i] = wr[(size_t)r0 * 192 + i];
    __syncthreads();

    // per-row stats: 32 threads per row
    {
        int row = t >> 5, j = t & 31;
        float a0 = in_s[row*192 + j],      a1 = in_s[row*192 + 32 + j];
        float f2p = a0*a0 + a1*a1;
        float ampp = in_s[row*192 + 64 + j] + in_s[row*192 + 96 + j];
        #pragma unroll
        for (int m = 16; m >= 1; m >>= 1) {
            f2p  += __shfl_xor(f2p, m);
            ampp += __shfl_xor(ampp, m);
        }
        if (j == 0) {
            float la = log1pf(ampp);
            la_s[row] = la;
            rowstats[(size_t)(r0+row)*2]     = f2p;
            rowstats[(size_t)(r0+row)*2 + 1] = la;
        }
    }
    const float rw1 = rw[1], rw2 = rw[2];

    float acc[RP_ROWS], res[RP_ROWS];

    // layer 0: (192 -> 256)
    #pragma unroll
    for (int r = 0; r < RP_ROWS; ++r) acc[r] = 0.f;
    for (int k = 0; k < 192; ++k) {
        float w = W0[k*256 + t];
        #pragma unroll
        for (int r = 0; r < RP_ROWS; ++r) acc[r] += in_s[r*192 + k] * w;
    }
    {
        float bb = b0[t];
        #pragma unroll
        for (int r = 0; r < RP_ROWS; ++r) {
            float v = gelu_exact(acc[r] + bb);
            res[r] = v; x_s[r*256 + t] = v;
        }
    }
    __syncthreads();

    // layer 1
    #pragma unroll
    for (int r = 0; r < RP_ROWS; ++r) acc[r] = 0.f;
    for (int k = 0; k < 256; ++k) {
        float w = W1[k*256 + t];
        #pragma unroll
        for (int r = 0; r < RP_ROWS; ++r) acc[r] += x_s[r*256 + k] * w;
    }
    {
        float bb = b1[t];
        #pragma unroll
        for (int r = 0; r < RP_ROWS; ++r) {
            float v = gelu_exact(acc[r] + bb) + rw1 * res[r];
            res[r] = v; y_s[r*256 + t] = v;
        }
    }
    __syncthreads();

    // layer 2
    #pragma unroll
    for (int r = 0; r < RP_ROWS; ++r) acc[r] = 0.f;
    for (int k = 0; k < 256; ++k) {
        float w = W2[k*256 + t];
        #pragma unroll
        for (int r = 0; r < RP_ROWS; ++r) acc[r] += y_s[r*256 + k] * w;
    }
    {
        float bb = b2[t];
        #pragma unroll
        for (int r = 0; r < RP_ROWS; ++r) {
            float v = gelu_exact(acc[r] + bb) + rw2 * res[r];
            res[r] = v;   // res now holds final x
        }
    }

    // write A: x part (cols 192..447), scaled by 0.1
    #pragma unroll
    for (int r = 0; r < RP_ROWS; ++r)
        Ag[(size_t)(r0+r)*ASTRIDE + 192 + t] = f2bf(0.1f * res[r]);

    // write A: freqs / scaled cos / scaled sin (cols 0..191)
    if (t < 64) {
        #pragma unroll
        for (int r = 0; r < RP_ROWS; ++r)
            Ag[(size_t)(r0+r)*ASTRIDE + t] = f2bf(in_s[r*192 + t]);
    } else if (t < 128) {
        int h = t - 64;
        #pragma unroll
        for (int r = 0; r < RP_ROWS; ++r) {
            float sc = (0.5f/64.f) * la_s[r];
            Ag[(size_t)(r0+r)*ASTRIDE + t] = f2bf(cosf(in_s[r*192 + 128 + h]) * sc);
        }
    } else if (t < 192) {
        int h = t - 128;
        #pragma unroll
        for (int r = 0; r < RP_ROWS; ++r) {
            float sc = (0.5f/64.f) * la_s[r];
            Ag[(size_t)(r0+r)*ASTRIDE + t] = f2bf(sinf(in_s[r*192 + 128 + h]) * sc);
        }
    }
}

// ---------- kernel 2: vocab prep (B matrix + v2) ----------
__global__ __launch_bounds__(256) void vocab_prep(
    const float* __restrict__ vf, const float* __restrict__ vp,
    const float* __restrict__ Wv,
    u16* __restrict__ Bg, float* __restrict__ v2)
{
    const int t = threadIdx.x;
    const int v0 = blockIdx.x * 64;

    // freqs + v2 + phases: 4 threads per vocab row
    {
        int v = v0 + (t >> 2);
        int q = t & 3;
        const float4* src = (const float4*)(vf + (size_t)v*64 + q*16);
        float ss = 0.f;
        u16 tf[16];
        #pragma unroll
        for (int i = 0; i < 4; ++i) {
            float4 x = src[i];
            ss += x.x*x.x + x.y*x.y + x.z*x.z + x.w*x.w;
            tf[i*4+0] = f2bf(x.x); tf[i*4+1] = f2bf(x.y);
            tf[i*4+2] = f2bf(x.z); tf[i*4+3] = f2bf(x.w);
        }
        u16x8 o0, o1;
        #pragma unroll
        for (int e = 0; e < 8; ++e) { o0[e] = tf[e]; o1[e] = tf[8+e]; }
        u16x8* dst = (u16x8*)(Bg + (size_t)v*BSTRIDE + q*16);
        dst[0] = o0; dst[1] = o1;

        ss += __shfl_xor(ss, 1);
        ss += __shfl_xor(ss, 2);
        if (q == 0) v2[v] = ss;

        // phases -> cos, sin
        const float4* sp = (const float4*)(vp + (size_t)v*64 + q*16);
        u16 tc[16], ts[16];
        #pragma unroll
        for (int i = 0; i < 4; ++i) {
            float4 x = sp[i];
            tc[i*4+0] = f2bf(cosf(x.x)); ts[i*4+0] = f2bf(sinf(x.x));
            tc[i*4+1] = f2bf(cosf(x.y)); ts[i*4+1] = f2bf(sinf(x.y));
            tc[i*4+2] = f2bf(cosf(x.z)); ts[i*4+2] = f2bf(sinf(x.z));
            tc[i*4+3] = f2bf(cosf(x.w)); ts[i*4+3] = f2bf(sinf(x.w));
        }
        u16x8 c0, c1, s0, s1;
        #pragma unroll
        for (int e = 0; e < 8; ++e) { c0[e]=tc[e]; c1[e]=tc[8+e]; s0[e]=ts[e]; s1[e]=ts[8+e]; }
        u16x8* dc = (u16x8*)(Bg + (size_t)v*BSTRIDE + 64 + q*16);
        dc[0] = c0; dc[1] = c1;
        u16x8* dsn = (u16x8*)(Bg + (size_t)v*BSTRIDE + 128 + q*16);
        dsn[0] = s0; dsn[1] = s1;
    }

    // Wv columns -> B cols 192..447
    {
        int v  = v0 + (t & 63);
        int kb = (t >> 6) * 64;
        #pragma unroll
        for (int i = 0; i < 8; ++i) {
            u16 tmp[8];
            #pragma unroll
            for (int e = 0; e < 8; ++e) {
                int k = kb + i*8 + e;
                tmp[e] = f2bf(Wv[(size_t)k * VCOLS + v]);
            }
            u16x8 o;
            #pragma unroll
            for (int e = 0; e < 8; ++e) o[e] = tmp[e];
            *(u16x8*)(Bg + (size_t)v*BSTRIDE + 192 + kb + i*8) = o;
        }
    }
}

// ---------- kernel 3: main fused GEMM + epilogue ----------
// tile 64(M) x 128(N), BK=64, 4 waves (2x2), mfma 16x16x32
__global__ __launch_bounds__(256) void spectral_main(
    const u16* __restrict__ Ag, const u16* __restrict__ Bg,
    const float* __restrict__ rowstats, const float* __restrict__ v2,
    const float* __restrict__ bv, float* __restrict__ out)
{
    __shared__ u16 As[64][72];    // +8 pad: stride 144B kills the 16-lane bank collision
    __shared__ u16 Bs[128][72];

    const int tid = threadIdx.x;
    const int bid = blockIdx.x;
    const int tm = bid & 31;          // 32 M-tiles (fast dim: consecutive blocks share B tile)
    const int tn = bid >> 5;          // 250 N-tiles
    const int rowA0 = tm * 64;
    const int colB0 = tn * 128;

    const int w = tid >> 6, lane = tid & 63;
    const int wm = (w >> 1) * 32, wn = (w & 1) * 64;
    const int cg = lane >> 4, ln = lane & 15;

    f32x4 accC[2][4] = {};
    f32x4 accF[2][4] = {};

    auto stage = [&](int k0) {
        #pragma unroll
        for (int j = 0; j < 2; ++j) {
            int ch = tid + j*256;
            int r = ch >> 3, kb = (ch & 7) * 8;
            *(u16x8*)&As[r][kb] = *(const u16x8*)(Ag + (size_t)(rowA0 + r)*ASTRIDE + k0 + kb);
        }
        #pragma unroll
        for (int j = 0; j < 4; ++j) {
            int ch = tid + j*256;
            int r = ch >> 3, kb = (ch & 7) * 8;
            *(u16x8*)&Bs[r][kb] = *(const u16x8*)(Bg + (size_t)(colB0 + r)*BSTRIDE + k0 + kb);
        }
    };

    auto compute_step = [&](f32x4 (&ACC)[2][4]) {
        #pragma unroll
        for (int kk = 0; kk < 2; ++kk) {
            short8 a[2], b[4];
            #pragma unroll
            for (int fr = 0; fr < 2; ++fr)
                a[fr] = *(const short8*)&As[wm + fr*16 + ln][kk*32 + cg*8];
            #pragma unroll
            for (int fc = 0; fc < 4; ++fc)
                b[fc] = *(const short8*)&Bs[wn + fc*16 + ln][kk*32 + cg*8];
            #pragma unroll
            for (int fr = 0; fr < 2; ++fr)
                #pragma unroll
                for (int fc = 0; fc < 4; ++fc)
                    ACC[fr][fc] = __builtin_amdgcn_mfma_f32_16x16x32_bf16(
                        a[fr], b[fc], ACC[fr][fc], 0, 0, 0);
        }
    };

    // kt=0 -> cross accumulator (k 0..63); kt=1..6 -> fused accumulator
    for (int kt = 0; kt < 7; ++kt) {
        if (kt) __syncthreads();
        stage(kt * 64);
        __syncthreads();
        if (kt == 0) compute_step(accC); else compute_step(accF);
    }

    // epilogue
    float f2m[2][4], lam[2][4];
    #pragma unroll
    for (int fr = 0; fr < 2; ++fr)
        #pragma unroll
        for (int j = 0; j < 4; ++j) {
            int m = rowA0 + wm + fr*16 + cg*4 + j;
            f2m[fr][j] = rowstats[(size_t)2*m];
            lam[fr][j] = rowstats[(size_t)2*m + 1];
        }
    float v2n[4], bvn[4];
    #pragma unroll
    for (int fc = 0; fc < 4; ++fc) {
        int n = colB0 + wn + fc*16 + ln;
        v2n[fc] = v2[n];
        bvn[fc] = bv[n];
    }
    #pragma unroll
    for (int fr = 0; fr < 2; ++fr)
        #pragma unroll
        for (int fc = 0; fc < 4; ++fc)
            #pragma unroll
            for (int j = 0; j < 4; ++j) {
                int m = rowA0 + wm + fr*16 + cg*4 + j;
                int n = colB0 + wn + fc*16 + ln;
                float cross = accC[fr][fc][j];
                float arg = fmaxf(f2m[fr][j] + v2n[fc] - 2.0f*cross, 0.0f);
                float val = accF[fr][fc][j] + 0.1f*bvn[fc] - lam[fr][j]*sqrtf(arg);
                out[(size_t)m * VCOLS + n] = val;
            }
}

// ---------- launch ----------
extern "C" void kernel_launch(void* const* d_in, const int* in_sizes, int n_in,
                              void* d_out, int out_size, void* d_ws, size_t ws_size,
                              hipStream_t stream) {
    const float* wave_repr = (const float*)d_in[0];
    const float* vf  = (const float*)d_in[1];
    const float* vp  = (const float*)d_in[2];
    const float* W0  = (const float*)d_in[3];
    const float* b0  = (const float*)d_in[4];
    const float* W1  = (const float*)d_in[5];
    const float* b1  = (const float*)d_in[6];
    const float* W2  = (const float*)d_in[7];
    const float* b2  = (const float*)d_in[8];
    const float* Wv  = (const float*)d_in[9];
    const float* bv  = (const float*)d_in[10];
    const float* rw  = (const float*)d_in[11];
    float* out = (float*)d_out;

    // workspace layout (bytes)
    //   Ag:       0            .. 1,835,008   (2048*448*2)
    //   Bg:       1,835,008    .. 30,507,008  (32000*448*2)
    //   rowstats: 30,507,008   .. 30,523,392  (2048*2*4)
    //   v2:       30,523,392   .. 30,651,392  (32000*4)
    u16*   Ag       = (u16*)d_ws;
    u16*   Bg       = (u16*)((char*)d_ws + 1835008);
    float* rowstats = (float*)((char*)d_ws + 30507008);
    float* v2       = (float*)((char*)d_ws + 30523392);

    hipLaunchKernelGGL(row_prep, dim3(2048 / RP_ROWS), dim3(256), 0, stream,
                       wave_repr, W0, b0, W1, b1, W2, b2, rw, Ag, rowstats);
    hipLaunchKernelGGL(vocab_prep, dim3(VCOLS / 64), dim3(256), 0, stream,
                       vf, vp, Wv, Bg, v2);
    hipLaunchKernelGGL(spectral_main, dim3(32 * (VCOLS / 128)), dim3(256), 0, stream,
                       Ag, Bg, rowstats, v2, bv, out);
}

// Round 2
// 470.284 us; speedup vs baseline: 1.2570x; 1.2570x over previous
//
#include <hip/hip_runtime.h>
#include <hip/hip_bf16.h>

typedef unsigned short u16;
typedef __attribute__((ext_vector_type(8))) unsigned short u16x8;
typedef __attribute__((ext_vector_type(8))) short short8;
typedef __attribute__((ext_vector_type(4))) float f32x4;

#define VCOLS 32000
#define ASTRIDE 448
#define BSTRIDE 448

__device__ __forceinline__ u16 f2bf(float f) {
    union { float f; unsigned u; } x; x.f = f;
    unsigned r = x.u + 0x7FFF + ((x.u >> 16) & 1);
    return (u16)(r >> 16);
}

__device__ __forceinline__ float gelu_exact(float v) {
    return 0.5f * v * (1.0f + erff(v * 0.70710678118654752f));
}

__device__ __forceinline__ void gload_lds16(const void* g, void* l) {
    __builtin_amdgcn_global_load_lds(
        (const __attribute__((address_space(1))) unsigned int*)g,
        (__attribute__((address_space(3))) unsigned int*)l, 16, 0, 0);
}

// ---------- kernel 1: per-row prep (stats + MLP + swizzled A matrix) ----------
#define RP_ROWS 8
__global__ __launch_bounds__(256) void row_prep(
    const float* __restrict__ wr,
    const float* __restrict__ W0, const float* __restrict__ b0,
    const float* __restrict__ W1, const float* __restrict__ b1,
    const float* __restrict__ W2, const float* __restrict__ b2,
    const float* __restrict__ rw,
    u16* __restrict__ Ag, float* __restrict__ rowstats)
{
    __shared__ float in_s[RP_ROWS * 192];
    __shared__ float x_s[RP_ROWS * 256];
    __shared__ float y_s[RP_ROWS * 256];
    __shared__ u16  row_s[RP_ROWS][448];
    __shared__ float la_s[RP_ROWS];

    const int t = threadIdx.x;
    const int r0 = blockIdx.x * RP_ROWS;

    for (int i = t; i < RP_ROWS * 192; i += 256)
        in_s[i] = wr[(size_t)r0 * 192 + i];
    __syncthreads();

    // per-row stats: 32 threads per row
    {
        int row = t >> 5, j = t & 31;
        float a0 = in_s[row*192 + j],      a1 = in_s[row*192 + 32 + j];
        float f2p = a0*a0 + a1*a1;
        float ampp = in_s[row*192 + 64 + j] + in_s[row*192 + 96 + j];
        #pragma unroll
        for (int m = 16; m >= 1; m >>= 1) {
            f2p  += __shfl_xor(f2p, m);
            ampp += __shfl_xor(ampp, m);
        }
        if (j == 0) {
            float la = log1pf(ampp);
            la_s[row] = la;
            rowstats[(size_t)(r0+row)*2]     = f2p;
            rowstats[(size_t)(r0+row)*2 + 1] = la;
        }
    }
    const float rw1 = rw[1], rw2 = rw[2];

    float acc[RP_ROWS], res[RP_ROWS];

    // layer 0: (192 -> 256), k unrolled x16 for load ILP
    #pragma unroll
    for (int r = 0; r < RP_ROWS; ++r) acc[r] = 0.f;
    for (int k0 = 0; k0 < 192; k0 += 16) {
        float w[16];
        #pragma unroll
        for (int e = 0; e < 16; ++e) w[e] = W0[(k0+e)*256 + t];
        #pragma unroll
        for (int e = 0; e < 16; ++e) {
            #pragma unroll
            for (int r = 0; r < RP_ROWS; ++r) acc[r] += in_s[r*192 + k0 + e] * w[e];
        }
    }
    {
        float bb = b0[t];
        #pragma unroll
        for (int r = 0; r < RP_ROWS; ++r) {
            float v = gelu_exact(acc[r] + bb);
            res[r] = v; x_s[r*256 + t] = v;
        }
    }
    __syncthreads();

    // layer 1
    #pragma unroll
    for (int r = 0; r < RP_ROWS; ++r) acc[r] = 0.f;
    for (int k0 = 0; k0 < 256; k0 += 16) {
        float w[16];
        #pragma unroll
        for (int e = 0; e < 16; ++e) w[e] = W1[(k0+e)*256 + t];
        #pragma unroll
        for (int e = 0; e < 16; ++e) {
            #pragma unroll
            for (int r = 0; r < RP_ROWS; ++r) acc[r] += x_s[r*256 + k0 + e] * w[e];
        }
    }
    {
        float bb = b1[t];
        #pragma unroll
        for (int r = 0; r < RP_ROWS; ++r) {
            float v = gelu_exact(acc[r] + bb) + rw1 * res[r];
            res[r] = v; y_s[r*256 + t] = v;
        }
    }
    __syncthreads();

    // layer 2
    #pragma unroll
    for (int r = 0; r < RP_ROWS; ++r) acc[r] = 0.f;
    for (int k0 = 0; k0 < 256; k0 += 16) {
        float w[16];
        #pragma unroll
        for (int e = 0; e < 16; ++e) w[e] = W2[(k0+e)*256 + t];
        #pragma unroll
        for (int e = 0; e < 16; ++e) {
            #pragma unroll
            for (int r = 0; r < RP_ROWS; ++r) acc[r] += y_s[r*256 + k0 + e] * w[e];
        }
    }
    {
        float bb = b2[t];
        #pragma unroll
        for (int r = 0; r < RP_ROWS; ++r)
            res[r] = gelu_exact(acc[r] + bb) + rw2 * res[r];   // final x
    }

    // assemble bf16 rows in LDS (linear k layout)
    #pragma unroll
    for (int r = 0; r < RP_ROWS; ++r)
        row_s[r][192 + t] = f2bf(0.1f * res[r]);
    if (t < 64) {
        #pragma unroll
        for (int r = 0; r < RP_ROWS; ++r)
            row_s[r][t] = f2bf(in_s[r*192 + t]);
    } else if (t < 128) {
        int h = t - 64;
        #pragma unroll
        for (int r = 0; r < RP_ROWS; ++r) {
            float s, c; __sincosf(in_s[r*192 + 128 + h], &s, &c);
            row_s[r][t] = f2bf(c * (0.5f/64.f) * la_s[r]);
        }
    } else if (t < 192) {
        int h = t - 128;
        #pragma unroll
        for (int r = 0; r < RP_ROWS; ++r) {
            float s, c; __sincosf(in_s[r*192 + 128 + h], &s, &c);
            row_s[r][t] = f2bf(s * (0.5f/64.f) * la_s[r]);
        }
    }
    __syncthreads();

    // swizzled 16B-chunk writeout: chunk ac of kt-slice stored at position ac^(m&7)
    for (int idx = t; idx < RP_ROWS * 56; idx += 256) {
        int r = idx / 56, c = idx % 56;
        int kt = c >> 3, ac = c & 7;
        int m = r0 + r;
        u16x8 val = *(const u16x8*)&row_s[r][c*8];
        *(u16x8*)(Ag + (size_t)m*ASTRIDE + kt*64 + ((ac ^ (m & 7)) * 8)) = val;
    }
}

// ---------- kernel 2: vocab prep (swizzled B matrix + v2) ----------
__global__ __launch_bounds__(256) void vocab_prep(
    const float* __restrict__ vf, const float* __restrict__ vp,
    const float* __restrict__ Wv,
    u16* __restrict__ Bg, float* __restrict__ v2)
{
    const int t = threadIdx.x;
    const int v0 = blockIdx.x * 64;

    // freqs + v2 + phases: 4 threads per vocab row
    {
        int v = v0 + (t >> 2);
        int q = t & 3;
        int s = v & 7;
        u16x8* baseB = (u16x8*)(Bg + (size_t)v * BSTRIDE);   // 56 chunks of 16B

        const float4* src = (const float4*)(vf + (size_t)v*64 + q*16);
        float ss = 0.f;
        u16 tf[16];
        #pragma unroll
        for (int i = 0; i < 4; ++i) {
            float4 x = src[i];
            ss += x.x*x.x + x.y*x.y + x.z*x.z + x.w*x.w;
            tf[i*4+0] = f2bf(x.x); tf[i*4+1] = f2bf(x.y);
            tf[i*4+2] = f2bf(x.z); tf[i*4+3] = f2bf(x.w);
        }
        u16x8 o0, o1;
        #pragma unroll
        for (int e = 0; e < 8; ++e) { o0[e] = tf[e]; o1[e] = tf[8+e]; }
        baseB[(2*q) ^ s]     = o0;
        baseB[(2*q+1) ^ s]   = o1;

        ss += __shfl_xor(ss, 1);
        ss += __shfl_xor(ss, 2);
        if (q == 0) v2[v] = ss;

        const float4* sp = (const float4*)(vp + (size_t)v*64 + q*16);
        u16 tc[16], ts_[16];
        #pragma unroll
        for (int i = 0; i < 4; ++i) {
            float4 x = sp[i];
            float sn, cs;
            __sincosf(x.x, &sn, &cs); tc[i*4+0] = f2bf(cs); ts_[i*4+0] = f2bf(sn);
            __sincosf(x.y, &sn, &cs); tc[i*4+1] = f2bf(cs); ts_[i*4+1] = f2bf(sn);
            __sincosf(x.z, &sn, &cs); tc[i*4+2] = f2bf(cs); ts_[i*4+2] = f2bf(sn);
            __sincosf(x.w, &sn, &cs); tc[i*4+3] = f2bf(cs); ts_[i*4+3] = f2bf(sn);
        }
        u16x8 c0, c1, s0, s1;
        #pragma unroll
        for (int e = 0; e < 8; ++e) { c0[e]=tc[e]; c1[e]=tc[8+e]; s0[e]=ts_[e]; s1[e]=ts_[8+e]; }
        baseB[8  + ((2*q) ^ s)]   = c0;
        baseB[8  + ((2*q+1) ^ s)] = c1;
        baseB[16 + ((2*q) ^ s)]   = s0;
        baseB[16 + ((2*q+1) ^ s)] = s1;
    }

    // Wv columns -> kt slices 3..6
    {
        int v  = v0 + (t & 63);
        int s  = v & 7;
        int kt = 3 + (t >> 6);
        int kb = (t >> 6) * 64;
        u16x8* baseB = (u16x8*)(Bg + (size_t)v * BSTRIDE);
        #pragma unroll
        for (int i = 0; i < 8; ++i) {
            u16 tmp[8];
            #pragma unroll
            for (int e = 0; e < 8; ++e)
                tmp[e] = f2bf(Wv[(size_t)(kb + i*8 + e) * VCOLS + v]);
            u16x8 o;
            #pragma unroll
            for (int e = 0; e < 8; ++e) o[e] = tmp[e];
            baseB[kt*8 + (i ^ s)] = o;
        }
    }
}

// ---------- kernel 3: main fused GEMM + epilogue ----------
// 128x128 tile, BK=64, 4 waves (2x2), mfma 16x16x32, global_load_lds staging,
// single accumulator with mid-loop nonlinear transform after the cross slice.
__global__ __launch_bounds__(256) void spectral_main(
    const u16* __restrict__ Ag, const u16* __restrict__ Bg,
    const float* __restrict__ rowstats, const float* __restrict__ v2,
    const float* __restrict__ bv, float* __restrict__ out)
{
    __shared__ u16 As[128 * 64];
    __shared__ u16 Bs[128 * 64];

    // XCD-bijective swizzle: 4000 blocks, 8 XCDs, 500 each; N-fast within XCD
    const int bid = blockIdx.x;
    const int l   = (bid & 7) * 500 + (bid >> 3);
    const int tm  = l / 250;
    const int tn  = l % 250;
    const int rowA0 = tm * 128;
    const int colB0 = tn * 128;

    const int tid  = threadIdx.x;
    const int wv   = tid >> 6, lane = tid & 63;
    const int wm   = (wv >> 1) * 64, wn = (wv & 1) * 64;
    const int cg   = lane >> 4, ln = lane & 15;

    f32x4 acc[4][4] = {};

    auto stage = [&](int kt) {
        const u16* ab = Ag + (size_t)(rowA0 + wv*32 + (lane >> 3)) * ASTRIDE + kt*64 + (lane & 7)*8;
        u16* al = As + wv*2048 + lane*8;
        #pragma unroll
        for (int c = 0; c < 4; ++c)
            gload_lds16(ab + (size_t)c*8*ASTRIDE, al + c*512);
        const u16* bb = Bg + (size_t)(colB0 + wv*32 + (lane >> 3)) * BSTRIDE + kt*64 + (lane & 7)*8;
        u16* bl = Bs + wv*2048 + lane*8;
        #pragma unroll
        for (int c = 0; c < 4; ++c)
            gload_lds16(bb + (size_t)c*8*BSTRIDE, bl + c*512);
    };

    auto compute = [&]() {
        #pragma unroll
        for (int kk = 0; kk < 2; ++kk) {
            short8 a[4], b[4];
            #pragma unroll
            for (int fr = 0; fr < 4; ++fr) {
                int r = wm + fr*16 + ln;
                a[fr] = *(const short8*)&As[r*64 + (((kk*4 + cg) ^ (ln & 7)) * 8)];
            }
            #pragma unroll
            for (int fc = 0; fc < 4; ++fc) {
                int r = wn + fc*16 + ln;
                b[fc] = *(const short8*)&Bs[r*64 + (((kk*4 + cg) ^ (ln & 7)) * 8)];
            }
            #pragma unroll
            for (int fr = 0; fr < 4; ++fr)
                #pragma unroll
                for (int fc = 0; fc < 4; ++fc)
                    acc[fr][fc] = __builtin_amdgcn_mfma_f32_16x16x32_bf16(
                        a[fr], b[fc], acc[fr][fc], 0, 0, 0);
        }
    };

    // kt = 0: cross slice
    stage(0);
    __syncthreads();
    compute();

    // transform: acc <- 0.1*bv - lam*sqrt(max(f2 + v2 - 2*cross, 0))
    {
        float f2m[4][4], lam[4][4], v2n[4], bvn[4];
        #pragma unroll
        for (int fr = 0; fr < 4; ++fr)
            #pragma unroll
            for (int j = 0; j < 4; ++j) {
                int m = rowA0 + wm + fr*16 + cg*4 + j;
                f2m[fr][j] = rowstats[(size_t)2*m];
                lam[fr][j] = rowstats[(size_t)2*m + 1];
            }
        #pragma unroll
        for (int fc = 0; fc < 4; ++fc) {
            int n = colB0 + wn + fc*16 + ln;
            v2n[fc] = v2[n];
            bvn[fc] = bv[n];
        }
        #pragma unroll
        for (int fr = 0; fr < 4; ++fr)
            #pragma unroll
            for (int fc = 0; fc < 4; ++fc)
                #pragma unroll
                for (int j = 0; j < 4; ++j) {
                    float cross = acc[fr][fc][j];
                    float arg = fmaxf(f2m[fr][j] + v2n[fc] - 2.0f*cross, 0.0f);
                    acc[fr][fc][j] = 0.1f*bvn[fc] - lam[fr][j]*sqrtf(arg);
                }
    }

    // kt = 1..6: linear slices accumulate on top
    for (int kt = 1; kt < 7; ++kt) {
        __syncthreads();
        stage(kt);
        __syncthreads();
        compute();
    }

    // store
    #pragma unroll
    for (int fr = 0; fr < 4; ++fr)
        #pragma unroll
        for (int fc = 0; fc < 4; ++fc)
            #pragma unroll
            for (int j = 0; j < 4; ++j) {
                int m = rowA0 + wm + fr*16 + cg*4 + j;
                int n = colB0 + wn + fc*16 + ln;
                out[(size_t)m * VCOLS + n] = acc[fr][fc][j];
            }
}

// ---------- launch ----------
extern "C" void kernel_launch(void* const* d_in, const int* in_sizes, int n_in,
                              void* d_out, int out_size, void* d_ws, size_t ws_size,
                              hipStream_t stream) {
    const float* wave_repr = (const float*)d_in[0];
    const float* vf  = (const float*)d_in[1];
    const float* vp  = (const float*)d_in[2];
    const float* W0  = (const float*)d_in[3];
    const float* b0  = (const float*)d_in[4];
    const float* W1  = (const float*)d_in[5];
    const float* b1  = (const float*)d_in[6];
    const float* W2  = (const float*)d_in[7];
    const float* b2  = (const float*)d_in[8];
    const float* Wv  = (const float*)d_in[9];
    const float* bv  = (const float*)d_in[10];
    const float* rw  = (const float*)d_in[11];
    float* out = (float*)d_out;

    // workspace layout (bytes)
    //   Ag:       0            .. 1,835,008   (2048*448*2)
    //   Bg:       1,835,008    .. 30,507,008  (32000*448*2)
    //   rowstats: 30,507,008   .. 30,523,392  (2048*2*4)
    //   v2:       30,523,392   .. 30,651,392  (32000*4)
    u16*   Ag       = (u16*)d_ws;
    u16*   Bg       = (u16*)((char*)d_ws + 1835008);
    float* rowstats = (float*)((char*)d_ws + 30507008);
    float* v2       = (float*)((char*)d_ws + 30523392);

    hipLaunchKernelGGL(row_prep, dim3(2048 / RP_ROWS), dim3(256), 0, stream,
                       wave_repr, W0, b0, W1, b1, W2, b2, rw, Ag, rowstats);
    hipLaunchKernelGGL(vocab_prep, dim3(VCOLS / 64), dim3(256), 0, stream,
                       vf, vp, Wv, Bg, v2);
    hipLaunchKernelGGL(spectral_main, dim3(16 * 250), dim3(256), 0, stream,
                       Ag, Bg, rowstats, v2, bv, out);
}

// Round 4
// 458.636 us; speedup vs baseline: 1.2889x; 1.0254x over previous
//
#include <hip/hip_runtime.h>
#include <hip/hip_bf16.h>

typedef unsigned short u16;
typedef __attribute__((ext_vector_type(8))) unsigned short u16x8;
typedef __attribute__((ext_vector_type(8))) short short8;
typedef __attribute__((ext_vector_type(4))) float f32x4;

#define VCOLS 32000
#define ASTRIDE 448
#define BSTRIDE 448

__device__ __forceinline__ u16 f2bf(float f) {
    union { float f; unsigned u; } x; x.f = f;
    unsigned r = x.u + 0x7FFF + ((x.u >> 16) & 1);
    return (u16)(r >> 16);
}

__device__ __forceinline__ float gelu_exact(float v) {
    return 0.5f * v * (1.0f + erff(v * 0.70710678118654752f));
}

__device__ __forceinline__ void gload_lds16(const void* g, void* l) {
    __builtin_amdgcn_global_load_lds(
        (const __attribute__((address_space(1))) unsigned int*)g,
        (__attribute__((address_space(3))) unsigned int*)l, 16, 0, 0);
}

// ---------- kernel 1: per-row prep (stats + MLP + swizzled A matrix) ----------
#define RP_ROWS 8
__global__ __launch_bounds__(256) void row_prep(
    const float* __restrict__ wr,
    const float* __restrict__ W0, const float* __restrict__ b0,
    const float* __restrict__ W1, const float* __restrict__ b1,
    const float* __restrict__ W2, const float* __restrict__ b2,
    const float* __restrict__ rw,
    u16* __restrict__ Ag, float* __restrict__ rowstats)
{
    __shared__ float in_s[RP_ROWS * 192];
    __shared__ float x_s[RP_ROWS * 256];
    __shared__ float y_s[RP_ROWS * 256];
    __shared__ u16  row_s[RP_ROWS][448];
    __shared__ float la_s[RP_ROWS];

    const int t = threadIdx.x;
    const int r0 = blockIdx.x * RP_ROWS;

    for (int i = t; i < RP_ROWS * 192; i += 256)
        in_s[i] = wr[(size_t)r0 * 192 + i];
    __syncthreads();

    // per-row stats: 32 threads per row
    {
        int row = t >> 5, j = t & 31;
        float a0 = in_s[row*192 + j],      a1 = in_s[row*192 + 32 + j];
        float f2p = a0*a0 + a1*a1;
        float ampp = in_s[row*192 + 64 + j] + in_s[row*192 + 96 + j];
        #pragma unroll
        for (int m = 16; m >= 1; m >>= 1) {
            f2p  += __shfl_xor(f2p, m);
            ampp += __shfl_xor(ampp, m);
        }
        if (j == 0) {
            float la = log1pf(ampp);
            la_s[row] = la;
            rowstats[(size_t)(r0+row)*2]     = f2p;
            rowstats[(size_t)(r0+row)*2 + 1] = la;
        }
    }
    const float rw1 = rw[1], rw2 = rw[2];

    float acc[RP_ROWS], res[RP_ROWS];

    // layer 0: (192 -> 256), k unrolled x16 for load ILP
    #pragma unroll
    for (int r = 0; r < RP_ROWS; ++r) acc[r] = 0.f;
    for (int k0 = 0; k0 < 192; k0 += 16) {
        float w[16];
        #pragma unroll
        for (int e = 0; e < 16; ++e) w[e] = W0[(k0+e)*256 + t];
        #pragma unroll
        for (int e = 0; e < 16; ++e) {
            #pragma unroll
            for (int r = 0; r < RP_ROWS; ++r) acc[r] += in_s[r*192 + k0 + e] * w[e];
        }
    }
    {
        float bb = b0[t];
        #pragma unroll
        for (int r = 0; r < RP_ROWS; ++r) {
            float v = gelu_exact(acc[r] + bb);
            res[r] = v; x_s[r*256 + t] = v;
        }
    }
    __syncthreads();

    // layer 1
    #pragma unroll
    for (int r = 0; r < RP_ROWS; ++r) acc[r] = 0.f;
    for (int k0 = 0; k0 < 256; k0 += 16) {
        float w[16];
        #pragma unroll
        for (int e = 0; e < 16; ++e) w[e] = W1[(k0+e)*256 + t];
        #pragma unroll
        for (int e = 0; e < 16; ++e) {
            #pragma unroll
            for (int r = 0; r < RP_ROWS; ++r) acc[r] += x_s[r*256 + k0 + e] * w[e];
        }
    }
    {
        float bb = b1[t];
        #pragma unroll
        for (int r = 0; r < RP_ROWS; ++r) {
            float v = gelu_exact(acc[r] + bb) + rw1 * res[r];
            res[r] = v; y_s[r*256 + t] = v;
        }
    }
    __syncthreads();

    // layer 2
    #pragma unroll
    for (int r = 0; r < RP_ROWS; ++r) acc[r] = 0.f;
    for (int k0 = 0; k0 < 256; k0 += 16) {
        float w[16];
        #pragma unroll
        for (int e = 0; e < 16; ++e) w[e] = W2[(k0+e)*256 + t];
        #pragma unroll
        for (int e = 0; e < 16; ++e) {
            #pragma unroll
            for (int r = 0; r < RP_ROWS; ++r) acc[r] += y_s[r*256 + k0 + e] * w[e];
        }
    }
    {
        float bb = b2[t];
        #pragma unroll
        for (int r = 0; r < RP_ROWS; ++r)
            res[r] = gelu_exact(acc[r] + bb) + rw2 * res[r];   // final x
    }

    // assemble bf16 rows in LDS (linear k layout)
    #pragma unroll
    for (int r = 0; r < RP_ROWS; ++r)
        row_s[r][192 + t] = f2bf(0.1f * res[r]);
    if (t < 64) {
        #pragma unroll
        for (int r = 0; r < RP_ROWS; ++r)
            row_s[r][t] = f2bf(in_s[r*192 + t]);
    } else if (t < 128) {
        int h = t - 64;
        #pragma unroll
        for (int r = 0; r < RP_ROWS; ++r) {
            float s, c; __sincosf(in_s[r*192 + 128 + h], &s, &c);
            row_s[r][t] = f2bf(c * (0.5f/64.f) * la_s[r]);
        }
    } else if (t < 192) {
        int h = t - 128;
        #pragma unroll
        for (int r = 0; r < RP_ROWS; ++r) {
            float s, c; __sincosf(in_s[r*192 + 128 + h], &s, &c);
            row_s[r][t] = f2bf(s * (0.5f/64.f) * la_s[r]);
        }
    }
    __syncthreads();

    // swizzled 16B-chunk writeout: chunk ac of kt-slice stored at position ac^(m&7)
    for (int idx = t; idx < RP_ROWS * 56; idx += 256) {
        int r = idx / 56, c = idx % 56;
        int kt = c >> 3, ac = c & 7;
        int m = r0 + r;
        u16x8 val = *(const u16x8*)&row_s[r][c*8];
        *(u16x8*)(Ag + (size_t)m*ASTRIDE + kt*64 + ((ac ^ (m & 7)) * 8)) = val;
    }
}

// ---------- kernel 2: vocab prep (swizzled B matrix + v2) ----------
__global__ __launch_bounds__(256) void vocab_prep(
    const float* __restrict__ vf, const float* __restrict__ vp,
    const float* __restrict__ Wv,
    u16* __restrict__ Bg, float* __restrict__ v2)
{
    __shared__ float wv_s[64][68];   // 64 k-rows x 64 v (+4 pad: float4-aligned rows)

    const int t = threadIdx.x;
    const int v0 = blockIdx.x * 64;

    // freqs + v2 + phases: 4 threads per vocab row
    {
        int v = v0 + (t >> 2);
        int q = t & 3;
        int s = v & 7;
        u16x8* baseB = (u16x8*)(Bg + (size_t)v * BSTRIDE);   // 56 chunks of 16B

        const float4* src = (const float4*)(vf + (size_t)v*64 + q*16);
        float ss = 0.f;
        u16 tf[16];
        #pragma unroll
        for (int i = 0; i < 4; ++i) {
            float4 x = src[i];
            ss += x.x*x.x + x.y*x.y + x.z*x.z + x.w*x.w;
            tf[i*4+0] = f2bf(x.x); tf[i*4+1] = f2bf(x.y);
            tf[i*4+2] = f2bf(x.z); tf[i*4+3] = f2bf(x.w);
        }
        u16x8 o0, o1;
        #pragma unroll
        for (int e = 0; e < 8; ++e) { o0[e] = tf[e]; o1[e] = tf[8+e]; }
        baseB[(2*q) ^ s]     = o0;
        baseB[(2*q+1) ^ s]   = o1;

        ss += __shfl_xor(ss, 1);
        ss += __shfl_xor(ss, 2);
        if (q == 0) v2[v] = ss;

        const float4* sp = (const float4*)(vp + (size_t)v*64 + q*16);
        u16 tc[16], ts_[16];
        #pragma unroll
        for (int i = 0; i < 4; ++i) {
            float4 x = sp[i];
            float sn, cs;
            __sincosf(x.x, &sn, &cs); tc[i*4+0] = f2bf(cs); ts_[i*4+0] = f2bf(sn);
            __sincosf(x.y, &sn, &cs); tc[i*4+1] = f2bf(cs); ts_[i*4+1] = f2bf(sn);
            __sincosf(x.z, &sn, &cs); tc[i*4+2] = f2bf(cs); ts_[i*4+2] = f2bf(sn);
            __sincosf(x.w, &sn, &cs); tc[i*4+3] = f2bf(cs); ts_[i*4+3] = f2bf(sn);
        }
        u16x8 c0, c1, s0, s1;
        #pragma unroll
        for (int e = 0; e < 8; ++e) { c0[e]=tc[e]; c1[e]=tc[8+e]; s0[e]=ts_[e]; s1[e]=ts_[8+e]; }
        baseB[8  + ((2*q) ^ s)]   = c0;
        baseB[8  + ((2*q+1) ^ s)] = c1;
        baseB[16 + ((2*q) ^ s)]   = s0;
        baseB[16 + ((2*q+1) ^ s)] = s1;
    }

    // Wv -> kt slices 3..6, via coalesced float4 staging + LDS transpose
    for (int kc = 0; kc < 4; ++kc) {
        __syncthreads();
        {
            // stage Wv[kc*64 .. kc*64+63][v0 .. v0+63] : 4 float4 per thread, coalesced
            int r = t >> 2, q = t & 3;
            const float4* src = (const float4*)(Wv + (size_t)(kc*64 + r)*VCOLS + v0 + q*16);
            float4* dst = (float4*)&wv_s[r][q*16];
            dst[0] = src[0]; dst[1] = src[1]; dst[2] = src[2]; dst[3] = src[3];
        }
        __syncthreads();
        {
            int v = t & 63, g = t >> 6;          // g = 0..3 -> chunks 2g, 2g+1
            int s = (v0 + v) & 7;
            u16x8* baseB = (u16x8*)(Bg + (size_t)(v0 + v) * BSTRIDE);
            #pragma unroll
            for (int cc = 0; cc < 2; ++cc) {
                int ch = g*2 + cc;
                u16x8 o;
                #pragma unroll
                for (int e = 0; e < 8; ++e) o[e] = f2bf(wv_s[ch*8 + e][v]);
                baseB[(3 + kc)*8 + (ch ^ s)] = o;
            }
        }
    }
}

// ---------- kernel 3: main fused GEMM + epilogue ----------
// 128x128 tile, BK=64, 4 waves (2x2), mfma 16x16x32, global_load_lds staging,
// double-buffered LDS + counted vmcnt (loads stay in flight across barriers),
// single accumulator with mid-loop nonlinear transform after the cross slice.
__global__ __launch_bounds__(256, 2) void spectral_main(
    const u16* __restrict__ Ag, const u16* __restrict__ Bg,
    const float* __restrict__ rowstats, const float* __restrict__ v2,
    const float* __restrict__ bv, float* __restrict__ out)
{
    __shared__ u16 As[2][128 * 64];
    __shared__ u16 Bs[2][128 * 64];

    // XCD-bijective swizzle: 4000 blocks, 8 XCDs, 500 each; N-fast within XCD
    const int bid = blockIdx.x;
    const int l   = (bid & 7) * 500 + (bid >> 3);
    const int tm  = l / 250;
    const int tn  = l % 250;
    const int rowA0 = tm * 128;
    const int colB0 = tn * 128;

    const int tid  = threadIdx.x;
    const int wv   = tid >> 6, lane = tid & 63;
    const int wm   = (wv >> 1) * 64, wn = (wv & 1) * 64;
    const int cg   = lane >> 4, ln = lane & 15;

    f32x4 acc[4][4] = {};

    auto stage = [&](int kt, int buf) {
        const u16* ab = Ag + (size_t)(rowA0 + wv*32 + (lane >> 3)) * ASTRIDE + kt*64 + (lane & 7)*8;
        u16* al = As[buf] + wv*2048 + lane*8;
        #pragma unroll
        for (int c = 0; c < 4; ++c)
            gload_lds16(ab + (size_t)c*8*ASTRIDE, al + c*512);
        const u16* bb = Bg + (size_t)(colB0 + wv*32 + (lane >> 3)) * BSTRIDE + kt*64 + (lane & 7)*8;
        u16* bl = Bs[buf] + wv*2048 + lane*8;
        #pragma unroll
        for (int c = 0; c < 4; ++c)
            gload_lds16(bb + (size_t)c*8*BSTRIDE, bl + c*512);
    };

    auto compute = [&](int buf) {
        #pragma unroll
        for (int kk = 0; kk < 2; ++kk) {
            short8 a[4], b[4];
            #pragma unroll
            for (int fr = 0; fr < 4; ++fr) {
                int r = wm + fr*16 + ln;
                a[fr] = *(const short8*)&As[buf][r*64 + (((kk*4 + cg) ^ (ln & 7)) * 8)];
            }
            #pragma unroll
            for (int fc = 0; fc < 4; ++fc) {
                int r = wn + fc*16 + ln;
                b[fc] = *(const short8*)&Bs[buf][r*64 + (((kk*4 + cg) ^ (ln & 7)) * 8)];
            }
            #pragma unroll
            for (int fr = 0; fr < 4; ++fr)
                #pragma unroll
                for (int fc = 0; fc < 4; ++fc)
                    acc[fr][fc] = __builtin_amdgcn_mfma_f32_16x16x32_bf16(
                        a[fr], b[fc], acc[fr][fc], 0, 0, 0);
        }
    };

    stage(0, 0);
    int cur = 0;
    for (int kt = 0; kt < 7; ++kt) {
        if (kt < 6) {
            stage(kt + 1, cur ^ 1);
            asm volatile("s_waitcnt vmcnt(8)" ::: "memory");   // current buf's 8 loads done
        } else {
            asm volatile("s_waitcnt vmcnt(0)" ::: "memory");
        }
        __builtin_amdgcn_s_barrier();
        compute(cur);

        if (kt == 0) {
            // transform: acc <- 0.1*bv - lam*sqrt(max(f2 + v2 - 2*cross, 0))
            float f2m[4][4], lam[4][4], v2n[4], bvn[4];
            #pragma unroll
            for (int fr = 0; fr < 4; ++fr)
                #pragma unroll
                for (int j = 0; j < 4; ++j) {
                    int m = rowA0 + wm + fr*16 + cg*4 + j;
                    f2m[fr][j] = rowstats[(size_t)2*m];
                    lam[fr][j] = rowstats[(size_t)2*m + 1];
                }
            #pragma unroll
            for (int fc = 0; fc < 4; ++fc) {
                int n = colB0 + wn + fc*16 + ln;
                v2n[fc] = v2[n];
                bvn[fc] = bv[n];
            }
            #pragma unroll
            for (int fr = 0; fr < 4; ++fr)
                #pragma unroll
                for (int fc = 0; fc < 4; ++fc)
                    #pragma unroll
                    for (int j = 0; j < 4; ++j) {
                        float cross = acc[fr][fc][j];
                        float arg = fmaxf(f2m[fr][j] + v2n[fc] - 2.0f*cross, 0.0f);
                        acc[fr][fc][j] = 0.1f*bvn[fc] - lam[fr][j]*sqrtf(arg);
                    }
        }

        asm volatile("" ::: "memory");   // pin ds_reads before the release barrier
        __builtin_amdgcn_s_barrier();
        cur ^= 1;
    }

    // store
    #pragma unroll
    for (int fr = 0; fr < 4; ++fr)
        #pragma unroll
        for (int fc = 0; fc < 4; ++fc)
            #pragma unroll
            for (int j = 0; j < 4; ++j) {
                int m = rowA0 + wm + fr*16 + cg*4 + j;
                int n = colB0 + wn + fc*16 + ln;
                out[(size_t)m * VCOLS + n] = acc[fr][fc][j];
            }
}

// ---------- launch ----------
extern "C" void kernel_launch(void* const* d_in, const int* in_sizes, int n_in,
                              void* d_out, int out_size, void* d_ws, size_t ws_size,
                              hipStream_t stream) {
    const float* wave_repr = (const float*)d_in[0];
    const float* vf  = (const float*)d_in[1];
    const float* vp  = (const float*)d_in[2];
    const float* W0  = (const float*)d_in[3];
    const float* b0  = (const float*)d_in[4];
    const float* W1  = (const float*)d_in[5];
    const float* b1  = (const float*)d_in[6];
    const float* W2  = (const float*)d_in[7];
    const float* b2  = (const float*)d_in[8];
    const float* Wv  = (const float*)d_in[9];
    const float* bv  = (const float*)d_in[10];
    const float* rw  = (const float*)d_in[11];
    float* out = (float*)d_out;

    // workspace layout (bytes)
    //   Ag:       0            .. 1,835,008   (2048*448*2)
    //   Bg:       1,835,008    .. 30,507,008  (32000*448*2)
    //   rowstats: 30,507,008   .. 30,523,392  (2048*2*4)
    //   v2:       30,523,392   .. 30,651,392  (32000*4)
    u16*   Ag       = (u16*)d_ws;
    u16*   Bg       = (u16*)((char*)d_ws + 1835008);
    float* rowstats = (float*)((char*)d_ws + 30507008);
    float* v2       = (float*)((char*)d_ws + 30523392);

    hipLaunchKernelGGL(row_prep, dim3(2048 / RP_ROWS), dim3(256), 0, stream,
                       wave_repr, W0, b0, W1, b1, W2, b2, rw, Ag, rowstats);
    hipLaunchKernelGGL(vocab_prep, dim3(VCOLS / 64), dim3(256), 0, stream,
                       vf, vp, Wv, Bg, v2);
    hipLaunchKernelGGL(spectral_main, dim3(16 * 250), dim3(256), 0, stream,
                       Ag, Bg, rowstats, v2, bv, out);
}

// Round 5
// 446.429 us; speedup vs baseline: 1.3242x; 1.0273x over previous
//
#include <hip/hip_runtime.h>
#include <hip/hip_bf16.h>

typedef unsigned short u16;
typedef __attribute__((ext_vector_type(8))) unsigned short u16x8;
typedef __attribute__((ext_vector_type(8))) short short8;
typedef __attribute__((ext_vector_type(4))) float f32x4;

#define VCOLS 32000
#define ASTRIDE 448
#define BSTRIDE 448

__device__ __forceinline__ u16 f2bf(float f) {
    union { float f; unsigned u; } x; x.f = f;
    unsigned r = x.u + 0x7FFF + ((x.u >> 16) & 1);
    return (u16)(r >> 16);
}

__device__ __forceinline__ float gelu_exact(float v) {
    return 0.5f * v * (1.0f + erff(v * 0.70710678118654752f));
}

__device__ __forceinline__ void gload_lds16(const void* g, void* l) {
    __builtin_amdgcn_global_load_lds(
        (const __attribute__((address_space(1))) unsigned int*)g,
        (__attribute__((address_space(3))) unsigned int*)l, 16, 0, 0);
}

// ---------- kernel 1: per-row prep (stats + MLP + swizzled A matrix) ----------
#define RP_ROWS 8
__global__ __launch_bounds__(256) void row_prep(
    const float* __restrict__ wr,
    const float* __restrict__ W0, const float* __restrict__ b0,
    const float* __restrict__ W1, const float* __restrict__ b1,
    const float* __restrict__ W2, const float* __restrict__ b2,
    const float* __restrict__ rw,
    u16* __restrict__ Ag, float* __restrict__ rowstats)
{
    __shared__ float in_s[RP_ROWS * 192];
    __shared__ float x_s[RP_ROWS * 256];
    __shared__ float y_s[RP_ROWS * 256];
    __shared__ u16  row_s[RP_ROWS][448];
    __shared__ float la_s[RP_ROWS];

    const int t = threadIdx.x;
    const int r0 = blockIdx.x * RP_ROWS;

    for (int i = t; i < RP_ROWS * 192; i += 256)
        in_s[i] = wr[(size_t)r0 * 192 + i];
    __syncthreads();

    // per-row stats: 32 threads per row
    {
        int row = t >> 5, j = t & 31;
        float a0 = in_s[row*192 + j],      a1 = in_s[row*192 + 32 + j];
        float f2p = a0*a0 + a1*a1;
        float ampp = in_s[row*192 + 64 + j] + in_s[row*192 + 96 + j];
        #pragma unroll
        for (int m = 16; m >= 1; m >>= 1) {
            f2p  += __shfl_xor(f2p, m);
            ampp += __shfl_xor(ampp, m);
        }
        if (j == 0) {
            float la = log1pf(ampp);
            la_s[row] = la;
            rowstats[(size_t)(r0+row)*2]     = f2p;
            rowstats[(size_t)(r0+row)*2 + 1] = la;
        }
    }
    const float rw1 = rw[1], rw2 = rw[2];

    float acc[RP_ROWS], res[RP_ROWS];

    // layer 0: (192 -> 256), k unrolled x16 for load ILP
    #pragma unroll
    for (int r = 0; r < RP_ROWS; ++r) acc[r] = 0.f;
    for (int k0 = 0; k0 < 192; k0 += 16) {
        float w[16];
        #pragma unroll
        for (int e = 0; e < 16; ++e) w[e] = W0[(k0+e)*256 + t];
        #pragma unroll
        for (int e = 0; e < 16; ++e) {
            #pragma unroll
            for (int r = 0; r < RP_ROWS; ++r) acc[r] += in_s[r*192 + k0 + e] * w[e];
        }
    }
    {
        float bb = b0[t];
        #pragma unroll
        for (int r = 0; r < RP_ROWS; ++r) {
            float v = gelu_exact(acc[r] + bb);
            res[r] = v; x_s[r*256 + t] = v;
        }
    }
    __syncthreads();

    // layer 1
    #pragma unroll
    for (int r = 0; r < RP_ROWS; ++r) acc[r] = 0.f;
    for (int k0 = 0; k0 < 256; k0 += 16) {
        float w[16];
        #pragma unroll
        for (int e = 0; e < 16; ++e) w[e] = W1[(k0+e)*256 + t];
        #pragma unroll
        for (int e = 0; e < 16; ++e) {
            #pragma unroll
            for (int r = 0; r < RP_ROWS; ++r) acc[r] += x_s[r*256 + k0 + e] * w[e];
        }
    }
    {
        float bb = b1[t];
        #pragma unroll
        for (int r = 0; r < RP_ROWS; ++r) {
            float v = gelu_exact(acc[r] + bb) + rw1 * res[r];
            res[r] = v; y_s[r*256 + t] = v;
        }
    }
    __syncthreads();

    // layer 2
    #pragma unroll
    for (int r = 0; r < RP_ROWS; ++r) acc[r] = 0.f;
    for (int k0 = 0; k0 < 256; k0 += 16) {
        float w[16];
        #pragma unroll
        for (int e = 0; e < 16; ++e) w[e] = W2[(k0+e)*256 + t];
        #pragma unroll
        for (int e = 0; e < 16; ++e) {
            #pragma unroll
            for (int r = 0; r < RP_ROWS; ++r) acc[r] += y_s[r*256 + k0 + e] * w[e];
        }
    }
    {
        float bb = b2[t];
        #pragma unroll
        for (int r = 0; r < RP_ROWS; ++r)
            res[r] = gelu_exact(acc[r] + bb) + rw2 * res[r];   // final x
    }

    // assemble bf16 rows in LDS (linear k layout)
    #pragma unroll
    for (int r = 0; r < RP_ROWS; ++r)
        row_s[r][192 + t] = f2bf(0.1f * res[r]);
    if (t < 64) {
        #pragma unroll
        for (int r = 0; r < RP_ROWS; ++r)
            row_s[r][t] = f2bf(in_s[r*192 + t]);
    } else if (t < 128) {
        int h = t - 64;
        #pragma unroll
        for (int r = 0; r < RP_ROWS; ++r) {
            float s, c; __sincosf(in_s[r*192 + 128 + h], &s, &c);
            row_s[r][t] = f2bf(c * (0.5f/64.f) * la_s[r]);
        }
    } else if (t < 192) {
        int h = t - 128;
        #pragma unroll
        for (int r = 0; r < RP_ROWS; ++r) {
            float s, c; __sincosf(in_s[r*192 + 128 + h], &s, &c);
            row_s[r][t] = f2bf(s * (0.5f/64.f) * la_s[r]);
        }
    }
    __syncthreads();

    // swizzled 16B-chunk writeout: chunk ac of kt-slice stored at position ac^(m&7)
    for (int idx = t; idx < RP_ROWS * 56; idx += 256) {
        int r = idx / 56, c = idx % 56;
        int kt = c >> 3, ac = c & 7;
        int m = r0 + r;
        u16x8 val = *(const u16x8*)&row_s[r][c*8];
        *(u16x8*)(Ag + (size_t)m*ASTRIDE + kt*64 + ((ac ^ (m & 7)) * 8)) = val;
    }
}

// ---------- kernel 2: vocab prep (swizzled B matrix + v2) ----------
__global__ __launch_bounds__(256) void vocab_prep(
    const float* __restrict__ vf, const float* __restrict__ vp,
    const float* __restrict__ Wv,
    u16* __restrict__ Bg, float* __restrict__ v2)
{
    __shared__ float wv_s[64][68];   // 64 k-rows x 64 v (+4 pad: float4-aligned rows)

    const int t = threadIdx.x;
    const int v0 = blockIdx.x * 64;

    // freqs + v2 + phases: 4 threads per vocab row
    {
        int v = v0 + (t >> 2);
        int q = t & 3;
        int s = v & 7;
        u16x8* baseB = (u16x8*)(Bg + (size_t)v * BSTRIDE);   // 56 chunks of 16B

        const float4* src = (const float4*)(vf + (size_t)v*64 + q*16);
        float ss = 0.f;
        u16 tf[16];
        #pragma unroll
        for (int i = 0; i < 4; ++i) {
            float4 x = src[i];
            ss += x.x*x.x + x.y*x.y + x.z*x.z + x.w*x.w;
            tf[i*4+0] = f2bf(x.x); tf[i*4+1] = f2bf(x.y);
            tf[i*4+2] = f2bf(x.z); tf[i*4+3] = f2bf(x.w);
        }
        u16x8 o0, o1;
        #pragma unroll
        for (int e = 0; e < 8; ++e) { o0[e] = tf[e]; o1[e] = tf[8+e]; }
        baseB[(2*q) ^ s]     = o0;
        baseB[(2*q+1) ^ s]   = o1;

        ss += __shfl_xor(ss, 1);
        ss += __shfl_xor(ss, 2);
        if (q == 0) v2[v] = ss;

        const float4* sp = (const float4*)(vp + (size_t)v*64 + q*16);
        u16 tc[16], ts_[16];
        #pragma unroll
        for (int i = 0; i < 4; ++i) {
            float4 x = sp[i];
            float sn, cs;
            __sincosf(x.x, &sn, &cs); tc[i*4+0] = f2bf(cs); ts_[i*4+0] = f2bf(sn);
            __sincosf(x.y, &sn, &cs); tc[i*4+1] = f2bf(cs); ts_[i*4+1] = f2bf(sn);
            __sincosf(x.z, &sn, &cs); tc[i*4+2] = f2bf(cs); ts_[i*4+2] = f2bf(sn);
            __sincosf(x.w, &sn, &cs); tc[i*4+3] = f2bf(cs); ts_[i*4+3] = f2bf(sn);
        }
        u16x8 c0, c1, s0, s1;
        #pragma unroll
        for (int e = 0; e < 8; ++e) { c0[e]=tc[e]; c1[e]=tc[8+e]; s0[e]=ts_[e]; s1[e]=ts_[8+e]; }
        baseB[8  + ((2*q) ^ s)]   = c0;
        baseB[8  + ((2*q+1) ^ s)] = c1;
        baseB[16 + ((2*q) ^ s)]   = s0;
        baseB[16 + ((2*q+1) ^ s)] = s1;
    }

    // Wv -> kt slices 3..6, via coalesced float4 staging + LDS transpose
    for (int kc = 0; kc < 4; ++kc) {
        __syncthreads();
        {
            // stage Wv[kc*64 .. kc*64+63][v0 .. v0+63] : 4 float4 per thread, coalesced
            int r = t >> 2, q = t & 3;
            const float4* src = (const float4*)(Wv + (size_t)(kc*64 + r)*VCOLS + v0 + q*16);
            float4* dst = (float4*)&wv_s[r][q*16];
            dst[0] = src[0]; dst[1] = src[1]; dst[2] = src[2]; dst[3] = src[3];
        }
        __syncthreads();
        {
            int v = t & 63, g = t >> 6;          // g = 0..3 -> chunks 2g, 2g+1
            int s = (v0 + v) & 7;
            u16x8* baseB = (u16x8*)(Bg + (size_t)(v0 + v) * BSTRIDE);
            #pragma unroll
            for (int cc = 0; cc < 2; ++cc) {
                int ch = g*2 + cc;
                u16x8 o;
                #pragma unroll
                for (int e = 0; e < 8; ++e) o[e] = f2bf(wv_s[ch*8 + e][v]);
                baseB[(3 + kc)*8 + (ch ^ s)] = o;
            }
        }
    }
}

// ---------- kernel 3: main fused GEMM + epilogue ----------
// m97 shape: 128x128 tile, BK=64, 4 waves (2x2), mfma 16x16x32,
// SINGLE-buffered 32 KB LDS (3 blocks/CU via launch_bounds), global_load_lds
// staging issued after the release barrier, __syncthreads drain per step.
// Single accumulator with mid-loop nonlinear transform after the cross slice.
__global__ __launch_bounds__(256, 3) void spectral_main(
    const u16* __restrict__ Ag, const u16* __restrict__ Bg,
    const float* __restrict__ rowstats, const float* __restrict__ v2,
    const float* __restrict__ bv, float* __restrict__ out)
{
    __shared__ u16 As[128 * 64];
    __shared__ u16 Bs[128 * 64];

    // XCD-bijective swizzle: 4000 blocks, 8 XCDs, 500 each; N-fast within XCD
    const int bid = blockIdx.x;
    const int l   = (bid & 7) * 500 + (bid >> 3);
    const int tm  = l / 250;
    const int tn  = l % 250;
    const int rowA0 = tm * 128;
    const int colB0 = tn * 128;

    const int tid  = threadIdx.x;
    const int wv   = tid >> 6, lane = tid & 63;
    const int wm   = (wv >> 1) * 64, wn = (wv & 1) * 64;
    const int cg   = lane >> 4, ln = lane & 15;

    f32x4 acc[4][4] = {};

    auto stage = [&](int kt) {
        const u16* ab = Ag + (size_t)(rowA0 + wv*32 + (lane >> 3)) * ASTRIDE + kt*64 + (lane & 7)*8;
        u16* al = As + wv*2048 + lane*8;
        #pragma unroll
        for (int c = 0; c < 4; ++c)
            gload_lds16(ab + (size_t)c*8*ASTRIDE, al + c*512);
        const u16* bb = Bg + (size_t)(colB0 + wv*32 + (lane >> 3)) * BSTRIDE + kt*64 + (lane & 7)*8;
        u16* bl = Bs + wv*2048 + lane*8;
        #pragma unroll
        for (int c = 0; c < 4; ++c)
            gload_lds16(bb + (size_t)c*8*BSTRIDE, bl + c*512);
    };

    auto compute = [&]() {
        #pragma unroll
        for (int kk = 0; kk < 2; ++kk) {
            short8 a[4], b[4];
            #pragma unroll
            for (int fr = 0; fr < 4; ++fr) {
                int r = wm + fr*16 + ln;
                a[fr] = *(const short8*)&As[r*64 + (((kk*4 + cg) ^ (ln & 7)) * 8)];
            }
            #pragma unroll
            for (int fc = 0; fc < 4; ++fc) {
                int r = wn + fc*16 + ln;
                b[fc] = *(const short8*)&Bs[r*64 + (((kk*4 + cg) ^ (ln & 7)) * 8)];
            }
            #pragma unroll
            for (int fr = 0; fr < 4; ++fr)
                #pragma unroll
                for (int fc = 0; fc < 4; ++fc)
                    acc[fr][fc] = __builtin_amdgcn_mfma_f32_16x16x32_bf16(
                        a[fr], b[fc], acc[fr][fc], 0, 0, 0);
        }
    };

    stage(0);
    for (int kt = 0; kt < 7; ++kt) {
        __syncthreads();            // drains vmcnt(0): this tile's loads complete
        compute();

        if (kt == 0) {
            // transform: acc <- 0.1*bv - lam*sqrt(max(f2 + v2 - 2*cross, 0))
            float f2m[4][4], lam[4][4], v2n[4], bvn[4];
            #pragma unroll
            for (int fr = 0; fr < 4; ++fr)
                #pragma unroll
                for (int j = 0; j < 4; ++j) {
                    int m = rowA0 + wm + fr*16 + cg*4 + j;
                    f2m[fr][j] = rowstats[(size_t)2*m];
                    lam[fr][j] = rowstats[(size_t)2*m + 1];
                }
            #pragma unroll
            for (int fc = 0; fc < 4; ++fc) {
                int n = colB0 + wn + fc*16 + ln;
                v2n[fc] = v2[n];
                bvn[fc] = bv[n];
            }
            #pragma unroll
            for (int fr = 0; fr < 4; ++fr)
                #pragma unroll
                for (int fc = 0; fc < 4; ++fc)
                    #pragma unroll
                    for (int j = 0; j < 4; ++j) {
                        float cross = acc[fr][fc][j];
                        float arg = fmaxf(f2m[fr][j] + v2n[fc] - 2.0f*cross, 0.0f);
                        acc[fr][fc][j] = 0.1f*bvn[fc] - lam[fr][j]*sqrtf(arg);
                    }
        }

        __syncthreads();            // all waves done reading LDS
        if (kt < 6) stage(kt + 1);  // refill the single buffer
    }

    // store
    #pragma unroll
    for (int fr = 0; fr < 4; ++fr)
        #pragma unroll
        for (int fc = 0; fc < 4; ++fc)
            #pragma unroll
            for (int j = 0; j < 4; ++j) {
                int m = rowA0 + wm + fr*16 + cg*4 + j;
                int n = colB0 + wn + fc*16 + ln;
                out[(size_t)m * VCOLS + n] = acc[fr][fc][j];
            }
}

// ---------- launch ----------
extern "C" void kernel_launch(void* const* d_in, const int* in_sizes, int n_in,
                              void* d_out, int out_size, void* d_ws, size_t ws_size,
                              hipStream_t stream) {
    const float* wave_repr = (const float*)d_in[0];
    const float* vf  = (const float*)d_in[1];
    const float* vp  = (const float*)d_in[2];
    const float* W0  = (const float*)d_in[3];
    const float* b0  = (const float*)d_in[4];
    const float* W1  = (const float*)d_in[5];
    const float* b1  = (const float*)d_in[6];
    const float* W2  = (const float*)d_in[7];
    const float* b2  = (const float*)d_in[8];
    const float* Wv  = (const float*)d_in[9];
    const float* bv  = (const float*)d_in[10];
    const float* rw  = (const float*)d_in[11];
    float* out = (float*)d_out;

    // workspace layout (bytes)
    //   Ag:       0            .. 1,835,008   (2048*448*2)
    //   Bg:       1,835,008    .. 30,507,008  (32000*448*2)
    //   rowstats: 30,507,008   .. 30,523,392  (2048*2*4)
    //   v2:       30,523,392   .. 30,651,392  (32000*4)
    u16*   Ag       = (u16*)d_ws;
    u16*   Bg       = (u16*)((char*)d_ws + 1835008);
    float* rowstats = (float*)((char*)d_ws + 30507008);
    float* v2       = (float*)((char*)d_ws + 30523392);

    hipLaunchKernelGGL(row_prep, dim3(2048 / RP_ROWS), dim3(256), 0, stream,
                       wave_repr, W0, b0, W1, b1, W2, b2, rw, Ag, rowstats);
    hipLaunchKernelGGL(vocab_prep, dim3(VCOLS / 64), dim3(256), 0, stream,
                       vf, vp, Wv, Bg, v2);
    hipLaunchKernelGGL(spectral_main, dim3(16 * 250), dim3(256), 0, stream,
                       Ag, Bg, rowstats, v2, bv, out);
}

// Round 6
// 432.187 us; speedup vs baseline: 1.3678x; 1.0330x over previous
//
#include <hip/hip_runtime.h>
#include <hip/hip_bf16.h>

typedef unsigned short u16;
typedef __attribute__((ext_vector_type(8))) unsigned short u16x8;
typedef __attribute__((ext_vector_type(8))) short short8;
typedef __attribute__((ext_vector_type(4))) float f32x4;

#define VCOLS 32000
#define ASTRIDE 448
#define BSTRIDE 448

__device__ __forceinline__ u16 f2bf(float f) {
    union { float f; unsigned u; } x; x.f = f;
    unsigned r = x.u + 0x7FFF + ((x.u >> 16) & 1);
    return (u16)(r >> 16);
}

__device__ __forceinline__ float gelu_exact(float v) {
    return 0.5f * v * (1.0f + erff(v * 0.70710678118654752f));
}

__device__ __forceinline__ void gload_lds16(const void* g, void* l) {
    __builtin_amdgcn_global_load_lds(
        (const __attribute__((address_space(1))) unsigned int*)g,
        (__attribute__((address_space(3))) unsigned int*)l, 16, 0, 0);
}

// ---------- merged prep kernel ----------
// blocks [0, 500)   : vocab mode (64 vocab rows each)
// blocks [500, 1012): row mode   (4 seq rows each, RP_ROWS=4)
#define RP_ROWS 4
#define NVBLK 500

struct RowSh {
    float in_s[RP_ROWS * 192];
    float x_s[RP_ROWS * 256];
    float y_s[RP_ROWS * 256];
    u16   row_s[RP_ROWS][448];
    float la_s[RP_ROWS];
};
struct VocSh {
    float wv[64][68];   // 64 k-rows x 64 v (+4 pad)
};
union PrepSh { RowSh r; VocSh v; };

__device__ void row_mode(PrepSh* sh, int rblk,
    const float* __restrict__ wr,
    const float* __restrict__ W0, const float* __restrict__ b0,
    const float* __restrict__ W1, const float* __restrict__ b1,
    const float* __restrict__ W2, const float* __restrict__ b2,
    const float* __restrict__ rw,
    u16* __restrict__ Ag, float* __restrict__ rowstats)
{
    RowSh& S = sh->r;
    const int t = threadIdx.x;
    const int r0 = rblk * RP_ROWS;

    for (int i = t; i < RP_ROWS * 192; i += 256)
        S.in_s[i] = wr[(size_t)r0 * 192 + i];
    __syncthreads();

    // per-row stats: one wave (64 lanes) per row
    {
        int row = t >> 6, j = t & 63;
        float f = S.in_s[row*192 + j];
        float f2p  = f * f;
        float ampp = S.in_s[row*192 + 64 + j];
        #pragma unroll
        for (int m = 32; m >= 1; m >>= 1) {
            f2p  += __shfl_xor(f2p, m);
            ampp += __shfl_xor(ampp, m);
        }
        if (j == 0) {
            float la = log1pf(ampp);
            S.la_s[row] = la;
            rowstats[(size_t)(r0+row)*2]     = f2p;
            rowstats[(size_t)(r0+row)*2 + 1] = la;
        }
    }
    const float rw1 = rw[1], rw2 = rw[2];

    float acc[RP_ROWS], res[RP_ROWS];

    // layer 0: (192 -> 256), k unrolled x16 for load ILP
    #pragma unroll
    for (int r = 0; r < RP_ROWS; ++r) acc[r] = 0.f;
    for (int k0 = 0; k0 < 192; k0 += 16) {
        float w[16];
        #pragma unroll
        for (int e = 0; e < 16; ++e) w[e] = W0[(k0+e)*256 + t];
        #pragma unroll
        for (int e = 0; e < 16; ++e) {
            #pragma unroll
            for (int r = 0; r < RP_ROWS; ++r) acc[r] += S.in_s[r*192 + k0 + e] * w[e];
        }
    }
    {
        float bb = b0[t];
        #pragma unroll
        for (int r = 0; r < RP_ROWS; ++r) {
            float v = gelu_exact(acc[r] + bb);
            res[r] = v; S.x_s[r*256 + t] = v;
        }
    }
    __syncthreads();

    // layer 1
    #pragma unroll
    for (int r = 0; r < RP_ROWS; ++r) acc[r] = 0.f;
    for (int k0 = 0; k0 < 256; k0 += 16) {
        float w[16];
        #pragma unroll
        for (int e = 0; e < 16; ++e) w[e] = W1[(k0+e)*256 + t];
        #pragma unroll
        for (int e = 0; e < 16; ++e) {
            #pragma unroll
            for (int r = 0; r < RP_ROWS; ++r) acc[r] += S.x_s[r*256 + k0 + e] * w[e];
        }
    }
    {
        float bb = b1[t];
        #pragma unroll
        for (int r = 0; r < RP_ROWS; ++r) {
            float v = gelu_exact(acc[r] + bb) + rw1 * res[r];
            res[r] = v; S.y_s[r*256 + t] = v;
        }
    }
    __syncthreads();

    // layer 2
    #pragma unroll
    for (int r = 0; r < RP_ROWS; ++r) acc[r] = 0.f;
    for (int k0 = 0; k0 < 256; k0 += 16) {
        float w[16];
        #pragma unroll
        for (int e = 0; e < 16; ++e) w[e] = W2[(k0+e)*256 + t];
        #pragma unroll
        for (int e = 0; e < 16; ++e) {
            #pragma unroll
            for (int r = 0; r < RP_ROWS; ++r) acc[r] += S.y_s[r*256 + k0 + e] * w[e];
        }
    }
    {
        float bb = b2[t];
        #pragma unroll
        for (int r = 0; r < RP_ROWS; ++r)
            res[r] = gelu_exact(acc[r] + bb) + rw2 * res[r];   // final x
    }

    // assemble bf16 rows in LDS (linear k layout)
    #pragma unroll
    for (int r = 0; r < RP_ROWS; ++r)
        S.row_s[r][192 + t] = f2bf(0.1f * res[r]);
    if (t < 64) {
        #pragma unroll
        for (int r = 0; r < RP_ROWS; ++r)
            S.row_s[r][t] = f2bf(S.in_s[r*192 + t]);
    } else if (t < 128) {
        int h = t - 64;
        #pragma unroll
        for (int r = 0; r < RP_ROWS; ++r) {
            float s, c; __sincosf(S.in_s[r*192 + 128 + h], &s, &c);
            S.row_s[r][t] = f2bf(c * (0.5f/64.f) * S.la_s[r]);
        }
    } else if (t < 192) {
        int h = t - 128;
        #pragma unroll
        for (int r = 0; r < RP_ROWS; ++r) {
            float s, c; __sincosf(S.in_s[r*192 + 128 + h], &s, &c);
            S.row_s[r][t] = f2bf(s * (0.5f/64.f) * S.la_s[r]);
        }
    }
    __syncthreads();

    // swizzled 16B-chunk writeout: chunk ac of kt-slice stored at position ac^(m&7)
    {
        int idx = t;                       // RP_ROWS*56 = 224 <= 256
        if (idx < RP_ROWS * 56) {
            int r = idx / 56, c = idx % 56;
            int kt = c >> 3, ac = c & 7;
            int m = r0 + r;
            u16x8 val = *(const u16x8*)&S.row_s[r][c*8];
            *(u16x8*)(Ag + (size_t)m*ASTRIDE + kt*64 + ((ac ^ (m & 7)) * 8)) = val;
        }
    }
}

__device__ void vocab_mode(PrepSh* sh, int vblk,
    const float* __restrict__ vf, const float* __restrict__ vp,
    const float* __restrict__ Wv,
    u16* __restrict__ Bg, float* __restrict__ v2)
{
    VocSh& S = sh->v;
    const int t = threadIdx.x;
    const int v0 = vblk * 64;

    // freqs + v2 + phases: 4 threads per vocab row
    {
        int v = v0 + (t >> 2);
        int q = t & 3;
        int s = v & 7;
        u16x8* baseB = (u16x8*)(Bg + (size_t)v * BSTRIDE);   // 56 chunks of 16B

        const float4* src = (const float4*)(vf + (size_t)v*64 + q*16);
        float ss = 0.f;
        u16 tf[16];
        #pragma unroll
        for (int i = 0; i < 4; ++i) {
            float4 x = src[i];
            ss += x.x*x.x + x.y*x.y + x.z*x.z + x.w*x.w;
            tf[i*4+0] = f2bf(x.x); tf[i*4+1] = f2bf(x.y);
            tf[i*4+2] = f2bf(x.z); tf[i*4+3] = f2bf(x.w);
        }
        u16x8 o0, o1;
        #pragma unroll
        for (int e = 0; e < 8; ++e) { o0[e] = tf[e]; o1[e] = tf[8+e]; }
        baseB[(2*q) ^ s]     = o0;
        baseB[(2*q+1) ^ s]   = o1;

        ss += __shfl_xor(ss, 1);
        ss += __shfl_xor(ss, 2);
        if (q == 0) v2[v] = ss;

        const float4* sp = (const float4*)(vp + (size_t)v*64 + q*16);
        u16 tc[16], ts_[16];
        #pragma unroll
        for (int i = 0; i < 4; ++i) {
            float4 x = sp[i];
            float sn, cs;
            __sincosf(x.x, &sn, &cs); tc[i*4+0] = f2bf(cs); ts_[i*4+0] = f2bf(sn);
            __sincosf(x.y, &sn, &cs); tc[i*4+1] = f2bf(cs); ts_[i*4+1] = f2bf(sn);
            __sincosf(x.z, &sn, &cs); tc[i*4+2] = f2bf(cs); ts_[i*4+2] = f2bf(sn);
            __sincosf(x.w, &sn, &cs); tc[i*4+3] = f2bf(cs); ts_[i*4+3] = f2bf(sn);
        }
        u16x8 c0, c1, s0, s1;
        #pragma unroll
        for (int e = 0; e < 8; ++e) { c0[e]=tc[e]; c1[e]=tc[8+e]; s0[e]=ts_[e]; s1[e]=ts_[8+e]; }
        baseB[8  + ((2*q) ^ s)]   = c0;
        baseB[8  + ((2*q+1) ^ s)] = c1;
        baseB[16 + ((2*q) ^ s)]   = s0;
        baseB[16 + ((2*q+1) ^ s)] = s1;
    }

    // Wv -> kt slices 3..6, via coalesced float4 staging + LDS transpose
    for (int kc = 0; kc < 4; ++kc) {
        __syncthreads();
        {
            int r = t >> 2, q = t & 3;
            const float4* src = (const float4*)(Wv + (size_t)(kc*64 + r)*VCOLS + v0 + q*16);
            float4* dst = (float4*)&S.wv[r][q*16];
            dst[0] = src[0]; dst[1] = src[1]; dst[2] = src[2]; dst[3] = src[3];
        }
        __syncthreads();
        {
            int v = t & 63, g = t >> 6;          // g = 0..3 -> chunks 2g, 2g+1
            int s = (v0 + v) & 7;
            u16x8* baseB = (u16x8*)(Bg + (size_t)(v0 + v) * BSTRIDE);
            #pragma unroll
            for (int cc = 0; cc < 2; ++cc) {
                int ch = g*2 + cc;
                u16x8 o;
                #pragma unroll
                for (int e = 0; e < 8; ++e) o[e] = f2bf(S.wv[ch*8 + e][v]);
                baseB[(3 + kc)*8 + (ch ^ s)] = o;
            }
        }
    }
}

__global__ __launch_bounds__(256) void prep_all(
    const float* __restrict__ wr,
    const float* __restrict__ W0, const float* __restrict__ b0,
    const float* __restrict__ W1, const float* __restrict__ b1,
    const float* __restrict__ W2, const float* __restrict__ b2,
    const float* __restrict__ rw,
    const float* __restrict__ vf, const float* __restrict__ vp,
    const float* __restrict__ Wv,
    u16* __restrict__ Ag, u16* __restrict__ Bg,
    float* __restrict__ rowstats, float* __restrict__ v2)
{
    __shared__ PrepSh sh;
    const int bid = blockIdx.x;
    if (bid < NVBLK)
        vocab_mode(&sh, bid, vf, vp, Wv, Bg, v2);
    else
        row_mode(&sh, bid - NVBLK, wr, W0, b0, W1, b1, W2, b2, rw, Ag, rowstats);
}

// ---------- main fused GEMM + epilogue (FROZEN from round 4) ----------
__global__ __launch_bounds__(256, 3) void spectral_main(
    const u16* __restrict__ Ag, const u16* __restrict__ Bg,
    const float* __restrict__ rowstats, const float* __restrict__ v2,
    const float* __restrict__ bv, float* __restrict__ out)
{
    __shared__ u16 As[128 * 64];
    __shared__ u16 Bs[128 * 64];

    // XCD-bijective swizzle: 4000 blocks, 8 XCDs, 500 each; N-fast within XCD
    const int bid = blockIdx.x;
    const int l   = (bid & 7) * 500 + (bid >> 3);
    const int tm  = l / 250;
    const int tn  = l % 250;
    const int rowA0 = tm * 128;
    const int colB0 = tn * 128;

    const int tid  = threadIdx.x;
    const int wv   = tid >> 6, lane = tid & 63;
    const int wm   = (wv >> 1) * 64, wn = (wv & 1) * 64;
    const int cg   = lane >> 4, ln = lane & 15;

    f32x4 acc[4][4] = {};

    auto stage = [&](int kt) {
        const u16* ab = Ag + (size_t)(rowA0 + wv*32 + (lane >> 3)) * ASTRIDE + kt*64 + (lane & 7)*8;
        u16* al = As + wv*2048 + lane*8;
        #pragma unroll
        for (int c = 0; c < 4; ++c)
            gload_lds16(ab + (size_t)c*8*ASTRIDE, al + c*512);
        const u16* bb = Bg + (size_t)(colB0 + wv*32 + (lane >> 3)) * BSTRIDE + kt*64 + (lane & 7)*8;
        u16* bl = Bs + wv*2048 + lane*8;
        #pragma unroll
        for (int c = 0; c < 4; ++c)
            gload_lds16(bb + (size_t)c*8*BSTRIDE, bl + c*512);
    };

    auto compute = [&]() {
        #pragma unroll
        for (int kk = 0; kk < 2; ++kk) {
            short8 a[4], b[4];
            #pragma unroll
            for (int fr = 0; fr < 4; ++fr) {
                int r = wm + fr*16 + ln;
                a[fr] = *(const short8*)&As[r*64 + (((kk*4 + cg) ^ (ln & 7)) * 8)];
            }
            #pragma unroll
            for (int fc = 0; fc < 4; ++fc) {
                int r = wn + fc*16 + ln;
                b[fc] = *(const short8*)&Bs[r*64 + (((kk*4 + cg) ^ (ln & 7)) * 8)];
            }
            #pragma unroll
            for (int fr = 0; fr < 4; ++fr)
                #pragma unroll
                for (int fc = 0; fc < 4; ++fc)
                    acc[fr][fc] = __builtin_amdgcn_mfma_f32_16x16x32_bf16(
                        a[fr], b[fc], acc[fr][fc], 0, 0, 0);
        }
    };

    stage(0);
    for (int kt = 0; kt < 7; ++kt) {
        __syncthreads();            // drains vmcnt(0): this tile's loads complete
        compute();

        if (kt == 0) {
            // transform: acc <- 0.1*bv - lam*sqrt(max(f2 + v2 - 2*cross, 0))
            float f2m[4][4], lam[4][4], v2n[4], bvn[4];
            #pragma unroll
            for (int fr = 0; fr < 4; ++fr)
                #pragma unroll
                for (int j = 0; j < 4; ++j) {
                    int m = rowA0 + wm + fr*16 + cg*4 + j;
                    f2m[fr][j] = rowstats[(size_t)2*m];
                    lam[fr][j] = rowstats[(size_t)2*m + 1];
                }
            #pragma unroll
            for (int fc = 0; fc < 4; ++fc) {
                int n = colB0 + wn + fc*16 + ln;
                v2n[fc] = v2[n];
                bvn[fc] = bv[n];
            }
            #pragma unroll
            for (int fr = 0; fr < 4; ++fr)
                #pragma unroll
                for (int fc = 0; fc < 4; ++fc)
                    #pragma unroll
                    for (int j = 0; j < 4; ++j) {
                        float cross = acc[fr][fc][j];
                        float arg = fmaxf(f2m[fr][j] + v2n[fc] - 2.0f*cross, 0.0f);
                        acc[fr][fc][j] = 0.1f*bvn[fc] - lam[fr][j]*sqrtf(arg);
                    }
        }

        __syncthreads();            // all waves done reading LDS
        if (kt < 6) stage(kt + 1);  // refill the single buffer
    }

    // store
    #pragma unroll
    for (int fr = 0; fr < 4; ++fr)
        #pragma unroll
        for (int fc = 0; fc < 4; ++fc)
            #pragma unroll
            for (int j = 0; j < 4; ++j) {
                int m = rowA0 + wm + fr*16 + cg*4 + j;
                int n = colB0 + wn + fc*16 + ln;
                out[(size_t)m * VCOLS + n] = acc[fr][fc][j];
            }
}

// ---------- launch ----------
extern "C" void kernel_launch(void* const* d_in, const int* in_sizes, int n_in,
                              void* d_out, int out_size, void* d_ws, size_t ws_size,
                              hipStream_t stream) {
    const float* wave_repr = (const float*)d_in[0];
    const float* vf  = (const float*)d_in[1];
    const float* vp  = (const float*)d_in[2];
    const float* W0  = (const float*)d_in[3];
    const float* b0  = (const float*)d_in[4];
    const float* W1  = (const float*)d_in[5];
    const float* b1  = (const float*)d_in[6];
    const float* W2  = (const float*)d_in[7];
    const float* b2  = (const float*)d_in[8];
    const float* Wv  = (const float*)d_in[9];
    const float* bv  = (const float*)d_in[10];
    const float* rw  = (const float*)d_in[11];
    float* out = (float*)d_out;

    // workspace layout (bytes)
    //   Ag:       0            .. 1,835,008   (2048*448*2)
    //   Bg:       1,835,008    .. 30,507,008  (32000*448*2)
    //   rowstats: 30,507,008   .. 30,523,392  (2048*2*4)
    //   v2:       30,523,392   .. 30,651,392  (32000*4)
    u16*   Ag       = (u16*)d_ws;
    u16*   Bg       = (u16*)((char*)d_ws + 1835008);
    float* rowstats = (float*)((char*)d_ws + 30507008);
    float* v2       = (float*)((char*)d_ws + 30523392);

    hipLaunchKernelGGL(prep_all, dim3(NVBLK + 2048 / RP_ROWS), dim3(256), 0, stream,
                       wave_repr, W0, b0, W1, b1, W2, b2, rw,
                       vf, vp, Wv, Ag, Bg, rowstats, v2);
    hipLaunchKernelGGL(spectral_main, dim3(16 * 250), dim3(256), 0, stream,
                       Ag, Bg, rowstats, v2, bv, out);
}